// Round 2
// 861.621 us; speedup vs baseline: 1.2053x; 1.2053x over previous
//
#include <hip/hip_runtime.h>
#include <stdint.h>

#define D_DIM   768
#define N_DIM   2304
#define M_DIM   65536
#define BM      128
#define BN      128
#define BK      64
#define NT_X    18                 // N tiles (2304/128)
#define MT_Y    512                // M tiles (65536/128)
#define NWG     (NT_X * MT_Y)      // 9216 blocks, 9216 % 8 == 0 -> bijective XCD swizzle
#define PER_XCD (NWG / 8)          // 1152

typedef short v8ss __attribute__((ext_vector_type(8)));
typedef float v4f  __attribute__((ext_vector_type(4)));

__device__ __forceinline__ unsigned short f2bf(float f) {
    union { float f; uint32_t u; } v; v.f = f;
    uint32_t r = v.u + 0x7fffu + ((v.u >> 16) & 1u);   // RNE
    return (unsigned short)(r >> 16);
}

// ---------------------------------------------------------------------------
// Kernel 1: W_eff[e][k] = W[e][k] + LoRA rank-4 update, cast to bf16.
// ---------------------------------------------------------------------------
__global__ void prep_w(const float* __restrict__ W,
                       const float* __restrict__ Aq, const float* __restrict__ Bq,
                       const float* __restrict__ Av, const float* __restrict__ Bv,
                       const float* __restrict__ s0,
                       unsigned short* __restrict__ Weff) {
    int idx = blockIdx.x * 256 + threadIdx.x;      // 0 .. 2304*768-1 (exact)
    int e = idx / D_DIM;
    int k = idx - e * D_DIM;
    float w = W[idx];
    float s = s0[0];
    if (e < D_DIM) {
        float acc = 0.f;
#pragma unroll
        for (int r = 0; r < 4; r++) acc += Bq[e * 4 + r] * Aq[r * D_DIM + k];
        w += s * acc;
    } else if (e >= 2 * D_DIM) {
        int d = e - 2 * D_DIM;
        float acc = 0.f;
#pragma unroll
        for (int r = 0; r < 4; r++) acc += Bv[d * 4 + r] * Av[r * D_DIM + k];
        w += s * acc;
    }
    Weff[idx] = f2bf(w);
}

// ---------------------------------------------------------------------------
// Kernel 2: x fp32 -> bf16. NT loads (native clang vector type — HIP float4
// is a class and __builtin_nontemporal_load rejects it): x is read once,
// keep L3 for xb (100 MB) which the GEMM re-reads 18x.
// ---------------------------------------------------------------------------
__global__ void convert_x(const float* __restrict__ x,
                          unsigned short* __restrict__ xb, int n4) {
    int stride = gridDim.x * blockDim.x;
    for (int i = blockIdx.x * blockDim.x + threadIdx.x; i < n4; i += stride) {
        v4f v = __builtin_nontemporal_load(((const v4f*)x) + i);
        ushort4 o;
        o.x = f2bf(v.x); o.y = f2bf(v.y); o.z = f2bf(v.z); o.w = f2bf(v.w);
        ((ushort4*)xb)[i] = o;
    }
}

// ---------------------------------------------------------------------------
// Kernel 3: GEMM  C[M,N] = Abf16[M,K] * Weff^T[K,N] + bias[N]
//   128x128 tile, 4 waves (2x2), BK=64, mfma_f32_16x16x32_bf16.
//   LDS rows are 128B; XOR swizzle chunk ^= (row&7) makes ds_read_b128
//   conflict-free (16 same-column lanes -> 8 distinct 16B slots, 2-way).
//   Swizzle applied on the GLOBAL source address (global_load_lds writes
//   linearly: wave-uniform base + lane*16) and on the ds_read address.
//   Output stores are nontemporal: keeps xb/Weff resident in L3/L2.
// ---------------------------------------------------------------------------
template <bool XB16>
__global__ __launch_bounds__(256, 4) void gemm_bt(const void* __restrict__ Aptr,
                                                  const unsigned short* __restrict__ Weff,
                                                  const float* __restrict__ bias,
                                                  float* __restrict__ out) {
    __shared__ __align__(16) unsigned short As[BM * BK];   // 16 KB, 128B rows
    __shared__ __align__(16) unsigned short Bs[BN * BK];   // 16 KB

    const int tid = threadIdx.x;
    const int l   = tid & 63;
    const int w   = tid >> 6;          // wave id 0..3
    const int wm  = w & 1;             // wave M position (0/1)
    const int wn  = w >> 1;            // wave N position (0/1)

    // Bijective XCD-chunked swizzle: each XCD gets a contiguous 64-m-row
    // stripe (n-fastest within), so its 4MB L2 holds Weff (3.5MB) + A panel.
    const int bid = blockIdx.x;
    const int swz = (bid & 7) * PER_XCD + (bid >> 3);
    const int by  = swz / NT_X;
    const int bx  = swz - by * NT_X;
    const int n0  = bx * BN;
    const int m0  = by * BM;

    v4f acc[4][4];
#pragma unroll
    for (int i = 0; i < 4; i++)
#pragma unroll
        for (int j = 0; j < 4; j++) acc[i][j] = (v4f){0.f, 0.f, 0.f, 0.f};

    const int lq  = l >> 4;            // quad 0..3
    const int l15 = l & 15;

    // Staging geometry: per wave-instr 8 rows x 128B (64 lanes x 16B).
    const int srow = w * 8 + (l >> 3);           // row within 32-row group
    const int sch  = (l & 7) ^ (l >> 3);         // inverse-swizzled src chunk
                                                 // (row&7 == l>>3 here)

    for (int k0 = 0; k0 < D_DIM; k0 += BK) {
        __syncthreads();   // prior iter's ds_reads complete before overwrite

        if (XB16) {
            const unsigned short* xb = (const unsigned short*)Aptr;
#pragma unroll
            for (int c = 0; c < 4; c++) {
                const unsigned short* g =
                    xb + (size_t)(m0 + c * 32 + srow) * D_DIM + k0 + sch * 8;
                __builtin_amdgcn_global_load_lds(
                    (const __attribute__((address_space(1))) void*)g,
                    (__attribute__((address_space(3))) void*)(As + c * 2048 + w * 512),
                    16, 0, 0);
            }
        } else {
            const float* x = (const float*)Aptr;
            const int r = tid >> 1;              // 0..127
            const int h = tid & 1;               // half of the 64-elem row
            const float* src = x + (size_t)(m0 + r) * D_DIM + k0 + h * 32;
#pragma unroll
            for (int j = 0; j < 4; j++) {
                float4 v0 = *(const float4*)(src + j * 8);
                float4 v1 = *(const float4*)(src + j * 8 + 4);
                int ch = h * 4 + j;
                int p  = ch ^ (r & 7);
                v8ss o;
                o[0] = (short)f2bf(v0.x); o[1] = (short)f2bf(v0.y);
                o[2] = (short)f2bf(v0.z); o[3] = (short)f2bf(v0.w);
                o[4] = (short)f2bf(v1.x); o[5] = (short)f2bf(v1.y);
                o[6] = (short)f2bf(v1.z); o[7] = (short)f2bf(v1.w);
                *(v8ss*)&As[r * 64 + p * 8] = o;
            }
        }

#pragma unroll
        for (int c = 0; c < 4; c++) {
            const unsigned short* g =
                Weff + (size_t)(n0 + c * 32 + srow) * D_DIM + k0 + sch * 8;
            __builtin_amdgcn_global_load_lds(
                (const __attribute__((address_space(1))) void*)g,
                (__attribute__((address_space(3))) void*)(Bs + c * 2048 + w * 512),
                16, 0, 0);
        }

        __syncthreads();   // drains vmcnt -> staged tiles visible

#pragma unroll
        for (int ks = 0; ks < 2; ks++) {
            v8ss af[4], bf[4];
#pragma unroll
            for (int mt = 0; mt < 4; mt++) {
                int r = wm * 64 + mt * 16 + l15;
                int p = (ks * 4 + lq) ^ (l15 & 7);      // r&7 == l15&7
                af[mt] = *(const v8ss*)&As[r * 64 + p * 8];
            }
#pragma unroll
            for (int nt = 0; nt < 4; nt++) {
                int r = wn * 64 + nt * 16 + l15;
                int p = (ks * 4 + lq) ^ (l15 & 7);
                bf[nt] = *(const v8ss*)&Bs[r * 64 + p * 8];
            }
#pragma unroll
            for (int mt = 0; mt < 4; mt++)
#pragma unroll
                for (int nt = 0; nt < 4; nt++)
                    acc[mt][nt] = __builtin_amdgcn_mfma_f32_16x16x32_bf16(
                        af[mt], bf[nt], acc[mt][nt], 0, 0, 0);
        }
    }

    // Epilogue: C/D layout col = l&15, row = (l>>4)*4 + i   [m89-verified]
    // Nontemporal: the 604MB output stream must not evict xb/Weff from L3.
#pragma unroll
    for (int nt = 0; nt < 4; nt++) {
        int col = n0 + wn * 64 + nt * 16 + l15;
        float bv = bias[col];
#pragma unroll
        for (int mt = 0; mt < 4; mt++) {
            int row = m0 + wm * 64 + mt * 16 + lq * 4;
            float* o = out + (size_t)row * N_DIM + col;
#pragma unroll
            for (int i = 0; i < 4; i++)
                __builtin_nontemporal_store(acc[mt][nt][i] + bv,
                                            o + (size_t)i * N_DIM);
        }
    }
}

// ---------------------------------------------------------------------------
extern "C" void kernel_launch(void* const* d_in, const int* in_sizes, int n_in,
                              void* d_out, int out_size, void* d_ws, size_t ws_size,
                              hipStream_t stream) {
    const float* x   = (const float*)d_in[0];
    const float* W   = (const float*)d_in[1];
    const float* b   = (const float*)d_in[2];
    const float* Aq  = (const float*)d_in[3];
    const float* Bq  = (const float*)d_in[4];
    const float* Av  = (const float*)d_in[5];
    const float* Bv  = (const float*)d_in[6];
    const float* s0  = (const float*)d_in[7];
    float* out = (float*)d_out;

    unsigned short* Weff = (unsigned short*)d_ws;
    const size_t weff_elems = (size_t)N_DIM * D_DIM;            // 1,769,472
    const size_t x_elems    = (size_t)M_DIM * D_DIM;            // 50,331,648
    const size_t need       = weff_elems * 2 + x_elems * 2;     // ~99.4 MiB

    prep_w<<<(int)(weff_elems / 256), 256, 0, stream>>>(W, Aq, Bq, Av, Bv, s0, Weff);

    if (ws_size >= need) {
        unsigned short* xb = Weff + weff_elems;
        convert_x<<<4096, 256, 0, stream>>>(x, xb, (int)(x_elems / 4));
        gemm_bt<true><<<NWG, 256, 0, stream>>>(xb, Weff, b, out);
    } else {
        gemm_bt<false><<<NWG, 256, 0, stream>>>(x, Weff, b, out);
    }
}